// Round 22
// baseline (108.681 us; speedup 1.0000x reference)
//
#include <hip/hip_runtime.h>
#include <hip/hip_bf16.h>
#include <math.h>

#define NN 8192
#define DD 64
// Block tile 256x32: 4 waves STACKED (each 64x32), all sharing one 4KB B
// tile -> cross-wave L1 reuse. Balanced single-round grid: 768 blocks
// (exactly 3/CU), blocks 0..511 do 22 tiles, 512..767 do 21. All blocks
// combo-pure (4224 = 22*192, 8448 = 22*384; 21-tile blocks start at 11264).
#define BJ_MAX 256              // 32-col tiles
#define T1B 4224                // sym tiles per combo: sum_{si<32}(256-8si)
#define T2B (2*T1B)             // 8448
#define TILES_TOTAL 16640       // 2*4224 + 32*256
#define NBLOCKS 768
#define EXT_CUT 512             // blocks < EXT_CUT run 22 tiles, else 21
#define NSLOT 32
#define SLOT_STRIDE 16          // floats -> 64B per slot

// Fragment-order layout: panel p = 16 source rows; chunk lane L holds
// row (p*16 + (L&15)), bf16 elems [ks*32 + (L>>4)*8, +8).
#define PANEL_ELEMS 1024        // 16 rows * 64 elems

typedef __bf16 bf16x8 __attribute__((ext_vector_type(8)));
typedef float f32x4 __attribute__((ext_vector_type(4)));

#if defined(__has_builtin)
#if __has_builtin(__builtin_amdgcn_exp2f)
#define EXP2F __builtin_amdgcn_exp2f
#endif
#endif
#ifndef EXP2F
#define EXP2F exp2f
#endif

// max3-friendly reductions (clang folds nested fmaxf to v_max3_f32)
#define FMAX3(a,b,c) fmaxf(fmaxf((a),(b)),(c))
#define FMAX4(a,b,c,d) fmaxf(FMAX3((a),(b),(c)),(d))

// ws layout:
//   [0,        1048576)  XbF bf16 [512 panels][2 ks][64 lanes][8]  (fragment order)
//   [1048576,  2097152)  ZbF bf16 same
//   [2097152, +32768)    na  f32  [8192]   ( = -log2(e) * ||x_i||^2 )
//   [+32768,  +65536)    nb  f32  [8192]
//   [+65536,  +71680)    partial f32 [3*NSLOT*SLOT_STRIDE]

__global__ __launch_bounds__(256) void prep_kernel(
        const float* __restrict__ X, const float* __restrict__ Z,
        __hip_bfloat16* __restrict__ XbF, __hip_bfloat16* __restrict__ ZbF,
        float* __restrict__ na, float* __restrict__ nb,
        float* __restrict__ partial) {
    int tid = threadIdx.x;
    int gw = blockIdx.x * 4 + (tid >> 6);    // panel index in [0, 1024)
    int lane = tid & 63;
    int lm = lane & 15, lk = lane >> 4;
    const float* src = (gw < 512) ? X : Z;
    __hip_bfloat16* dst = (gw < 512) ? XbF : ZbF;
    float* nrm = (gw < 512) ? na : nb;
    int p = (gw < 512) ? gw : gw - 512;
    int row = p * 16 + lm;

    float s = 0.f;
    #pragma unroll
    for (int ks = 0; ks < 2; ++ks) {
        const float4* q = (const float4*)(src + (size_t)row * DD + ks * 32 + lk * 8);
        float4 u = q[0], v = q[1];
        float w[8] = {u.x, u.y, u.z, u.w, v.x, v.y, v.z, v.w};
        unsigned int h[8];
        #pragma unroll
        for (int r = 0; r < 8; ++r) {
            __hip_bfloat16 b = __float2bfloat16(w[r]);
            h[r] = *(unsigned short*)&b;
            float xr = __bfloat162float(b);
            s = fmaf(xr, xr, s);
        }
        uint4 pk;
        pk.x = h[0] | (h[1] << 16); pk.y = h[2] | (h[3] << 16);
        pk.z = h[4] | (h[5] << 16); pk.w = h[6] | (h[7] << 16);
        *(uint4*)(dst + (size_t)p * PANEL_ELEMS + ks * 512 + lane * 8) = pk;
    }
    s += __shfl_xor(s, 16, 64);
    s += __shfl_xor(s, 32, 64);
    if (lk == 0) nrm[row] = -1.4426950408889634f * s;

    if (blockIdx.x == 0) {
        for (int i = tid; i < 3 * NSLOT * SLOT_STRIDE; i += 256) partial[i] = 0.f;
    }
}

// R19's structure + CROSS-TILE ACC DOUBLE-PIPELINE: two acc sets (accA/accB,
// static macro tokens). At iteration t: prefetch B(t+1), issue MFMA(t) into
// ACCCUR, then run the gate+epilogue of tile t-1 on ACCPRV -- whose MFMAs
// completed an iteration ago, so the max-tree + branch never wait on the
// matrix pipe and overlap MFMA(t)'s execution. Stripe changes (<=1/block)
// flush the pending tile eagerly before the nav reload (nav stays 1-copy).
// navrtmax de-materialized (recomputed in the rare open branch) to pay for
// the +32 VGPR second acc set under the (256,3) cap.
__global__ __launch_bounds__(256, 3) void mmd_kernel(
        const __hip_bfloat16* __restrict__ XbFh, const __hip_bfloat16* __restrict__ ZbFh,
        const float* __restrict__ na, const float* __restrict__ nb,
        float* __restrict__ partial) {
    int tid = threadIdx.x;
    int wave = tid >> 6, lane = tid & 63;
    int lm = lane & 15;   // frag row (within 16) / C col
    int lk = lane >> 4;   // k-group of 8 / C row group of 4
    __shared__ float wsum[4];
    const float C2 = 2.8853900817779268f;  // 2*log2(e)
    const int bid = blockIdx.x;
    const bool ext = (bid < EXT_CUT);      // 22 tiles if true, else 21

    // ---- map block's first tile (once) ----
    int t0 = bid * 21 + (ext ? bid : EXT_CUT);
    int combo, bi, bj;      // bi = 256-row stripe index
    if (t0 < T2B) {
        combo = (t0 < T1B) ? 0 : 1;
        int tt = t0 - (combo ? T1B : 0);
        // cum(si) = 260si - 4si^2
        int rr = (int)((65.0f - sqrtf(4225.0f - (float)tt)) * 0.5f);
        rr = rr < 0 ? 0 : (rr > 31 ? 31 : rr);
        while (rr > 0 && 260 * rr - 4 * rr * rr > tt) --rr;
        while (260 * (rr + 1) - 4 * (rr + 1) * (rr + 1) <= tt) ++rr;
        bi = rr;
        bj = 8 * rr + (tt - (260 * rr - 4 * rr * rr));
    } else {
        combo = 2;
        int rem = t0 - T2B;
        bi = rem >> 8;
        bj = rem & 255;
    }
    const bool sym = (combo != 2);
    const __bf16 *A, *B;
    const float *sa, *sb;
    const __bf16* XbF = (const __bf16*)XbFh;
    const __bf16* ZbF = (const __bf16*)ZbFh;
    if (combo == 0)      { A = XbF; B = XbF; sa = na; sb = na; }
    else if (combo == 1) { A = ZbF; B = ZbF; sa = nb; sb = nb; }
    else                 { A = XbF; B = ZbF; sa = na; sb = nb; }

    // ---- A fragments + row norms for current stripe ----
    bf16x8 af[2][4];
    float nav[4][4], navmax;
    {
        int pA = bi * 16 + wave * 4;
        #pragma unroll
        for (int ks = 0; ks < 2; ++ks)
            #pragma unroll
            for (int rt = 0; rt < 4; ++rt)
                af[ks][rt] = *(const bf16x8*)(A + (size_t)(pA + rt) * PANEL_ELEMS + ks * 512 + lane * 8);
        int row0 = bi * 256 + wave * 64;
        #pragma unroll
        for (int rt = 0; rt < 4; ++rt)
            #pragma unroll
            for (int r = 0; r < 4; ++r) nav[rt][r] = sa[row0 + rt * 16 + lk * 4 + r];
        navmax = fmaxf(fmaxf(FMAX4(nav[0][0], nav[0][1], nav[0][2], nav[0][3]),
                             FMAX4(nav[1][0], nav[1][1], nav[1][2], nav[1][3])),
                       fmaxf(FMAX4(nav[2][0], nav[2][1], nav[2][2], nav[2][3]),
                             FMAX4(nav[3][0], nav[3][1], nav[3][2], nav[3][3])));
    }

    // ---- prefetch B for first tile (32 cols: panels bj*2, bj*2+1) ----
    bf16x8 bufB[2][2][2];   // [buf][ks][ct]
    float bufNb[2][2];
    {
        int pB = bj * 2;
        #pragma unroll
        for (int ks = 0; ks < 2; ++ks)
            #pragma unroll
            for (int ct = 0; ct < 2; ++ct)
                bufB[0][ks][ct] = *(const bf16x8*)(B + (size_t)(pB + ct) * PANEL_ELEMS + ks * 512 + lane * 8);
        int col0 = bj * 32;
        #pragma unroll
        for (int ct = 0; ct < 2; ++ct) bufNb[0][ct] = sb[col0 + ct * 16 + lm];
    }

    float lsum = 0.f;
    f32x4 accA[4][2], accB[4][2];
    bool pend = false;
    int pbi = bi, pbj = bj;    // coords of the pending (deferred) tile

// Epilogue of a completed tile: acc set ACC, col-norms N0/N1, coords pbi/pbj.
// nav/navmax are guaranteed to match the pending tile's stripe (eager flush
// on stripe change keeps them coherent).
#define EPILOGUE_BODY(ACC, N0, N1)                                                   \
    {                                                                                \
        int prow0 = pbi * 256 + wave * 64;                                           \
        int pcol0 = pbj * 32;                                                        \
        bool pabove = sym && (pcol0 >= prow0 + 64);                                  \
        bool pelemw = sym && !pabove;                                                \
        float pScale = pabove ? 2.f : 1.f;                                           \
        float m00 = FMAX4(ACC[0][0][0], ACC[0][0][1], ACC[0][0][2], ACC[0][0][3]);   \
        float m01 = FMAX4(ACC[0][1][0], ACC[0][1][1], ACC[0][1][2], ACC[0][1][3]);   \
        float m10 = FMAX4(ACC[1][0][0], ACC[1][0][1], ACC[1][0][2], ACC[1][0][3]);   \
        float m11 = FMAX4(ACC[1][1][0], ACC[1][1][1], ACC[1][1][2], ACC[1][1][3]);   \
        float m20 = FMAX4(ACC[2][0][0], ACC[2][0][1], ACC[2][0][2], ACC[2][0][3]);   \
        float m21 = FMAX4(ACC[2][1][0], ACC[2][1][1], ACC[2][1][2], ACC[2][1][3]);   \
        float m30 = FMAX4(ACC[3][0][0], ACC[3][0][1], ACC[3][0][2], ACC[3][0][3]);   \
        float m31 = FMAX4(ACC[3][1][0], ACC[3][1][1], ACC[3][1][2], ACC[3][1][3]);   \
        float gmax = fmaxf(FMAX4(m00, m01, m10, m11), FMAX4(m20, m21, m30, m31));    \
        float nbmax = fmaxf((N0), (N1));                                             \
        float tileBound = fmaf(gmax, C2, navmax + nbmax);                            \
        if (__any(tileBound > -30.f)) {                                              \
            float pnv[2] = {(N0), (N1)};                                             \
            float prtmax[4];                                                         \
            _Pragma("unroll")                                                        \
            for (int rt = 0; rt < 4; ++rt)                                           \
                prtmax[rt] = FMAX4(nav[rt][0], nav[rt][1], nav[rt][2], nav[rt][3]);  \
            _Pragma("unroll")                                                        \
            for (int rt = 0; rt < 4; ++rt) {                                         \
                _Pragma("unroll")                                                    \
                for (int ct = 0; ct < 2; ++ct) {                                     \
                    float fm = FMAX4(ACC[rt][ct][0], ACC[rt][ct][1], ACC[rt][ct][2], ACC[rt][ct][3]); \
                    float fb = fmaf(fm, C2, prtmax[rt] + pnv[ct]);                   \
                    if (__any(fb > -30.f)) {                                         \
                        float base = pnv[ct];                                        \
                        float a0 = fmaf(ACC[rt][ct][0], C2, nav[rt][0] + base);      \
                        float a1 = fmaf(ACC[rt][ct][1], C2, nav[rt][1] + base);      \
                        float a2 = fmaf(ACC[rt][ct][2], C2, nav[rt][2] + base);      \
                        float a3 = fmaf(ACC[rt][ct][3], C2, nav[rt][3] + base);      \
                        float e0 = EXP2F(fminf(a0, 0.f));                            \
                        float e1 = EXP2F(fminf(a1, 0.f));                            \
                        float e2 = EXP2F(fminf(a2, 0.f));                            \
                        float e3 = EXP2F(fminf(a3, 0.f));                            \
                        if (pelemw) {                                                \
                            int gcol = pcol0 + ct * 16 + lm;                         \
                            int gr = prow0 + rt * 16 + lk * 4;                       \
                            e0 *= (gr + 0 < gcol) ? 2.f : ((gr + 0 == gcol) ? 1.f : 0.f); \
                            e1 *= (gr + 1 < gcol) ? 2.f : ((gr + 1 == gcol) ? 1.f : 0.f); \
                            e2 *= (gr + 2 < gcol) ? 2.f : ((gr + 2 == gcol) ? 1.f : 0.f); \
                            e3 *= (gr + 3 < gcol) ? 2.f : ((gr + 3 == gcol) ? 1.f : 0.f); \
                            lsum += (e0 + e1) + (e2 + e3);                           \
                        } else {                                                     \
                            lsum += pScale * ((e0 + e1) + (e2 + e3));                \
                        }                                                            \
                    }                                                                \
                }                                                                    \
            }                                                                        \
        }                                                                            \
    }

// One tile iteration. IT is a compile-time literal after unroll; ACCCUR/ACCPRV
// are static array names (rule #20: no runtime indexing of acc sets).
#define STEP_BODY(IT, ACCCUR, ACCPRV)                                                \
    if ((IT) < 21 || ext) {                                                          \
        const int cur = (IT) & 1, nxt = cur ^ 1;                                     \
        const bool havenext = ((IT) < 20) || ((IT) == 20 && ext);                    \
        /* snapshot prev tile's col-norms before prefetch clobbers the slot */       \
        float pn0 = bufNb[nxt][0], pn1 = bufNb[nxt][1];                              \
        int nbi = bi, nbj = bj;                                                      \
        if (havenext) {                                                              \
            nbj = bj + 1;                                                            \
            if (nbj == BJ_MAX) { nbi = bi + 1; nbj = sym ? 8 * nbi : 0; }            \
            int npB = nbj * 2;                                                       \
            _Pragma("unroll")                                                        \
            for (int ks = 0; ks < 2; ++ks)                                           \
                for (int ct = 0; ct < 2; ++ct)                                       \
                    bufB[nxt][ks][ct] = *(const bf16x8*)(B + (size_t)(npB + ct) * PANEL_ELEMS + ks * 512 + lane * 8); \
            int ncol0 = nbj * 32;                                                    \
            _Pragma("unroll")                                                        \
            for (int ct = 0; ct < 2; ++ct) bufNb[nxt][ct] = sb[ncol0 + ct * 16 + lm]; \
        }                                                                            \
        __builtin_amdgcn_sched_barrier(0);                                           \
        __builtin_amdgcn_s_setprio(1);                                               \
        _Pragma("unroll")                                                            \
        for (int rt = 0; rt < 4; ++rt)                                               \
            for (int ct = 0; ct < 2; ++ct)                                           \
                ACCCUR[rt][ct] = (f32x4){0.f, 0.f, 0.f, 0.f};                        \
        _Pragma("unroll")                                                            \
        for (int ks = 0; ks < 2; ++ks)                                               \
            for (int rt = 0; rt < 4; ++rt)                                           \
                for (int ct = 0; ct < 2; ++ct)                                       \
                    ACCCUR[rt][ct] = __builtin_amdgcn_mfma_f32_16x16x32_bf16(        \
                        af[ks][rt], bufB[cur][ks][ct], ACCCUR[rt][ct], 0, 0, 0);     \
        __builtin_amdgcn_s_setprio(0);                                               \
        /* deferred epilogue of tile IT-1: acc ready, overlaps MFMA above */         \
        if (pend) EPILOGUE_BODY(ACCPRV, pn0, pn1)                                    \
        /* current tile becomes pending */                                           \
        pbi = bi; pbj = bj; pend = true;                                             \
        if (havenext) {                                                              \
            if (nbi != bi) {                                                         \
                /* stripe change (<=1/block): flush eagerly before nav reload */     \
                EPILOGUE_BODY(ACCCUR, bufNb[cur][0], bufNb[cur][1])                  \
                pend = false;                                                        \
                int npA = nbi * 16 + wave * 4;                                       \
                _Pragma("unroll")                                                    \
                for (int ks = 0; ks < 2; ++ks)                                       \
                    for (int rt = 0; rt < 4; ++rt)                                   \
                        af[ks][rt] = *(const bf16x8*)(A + (size_t)(npA + rt) * PANEL_ELEMS + ks * 512 + lane * 8); \
                int nrow0 = nbi * 256 + wave * 64;                                   \
                _Pragma("unroll")                                                    \
                for (int rt = 0; rt < 4; ++rt)                                       \
                    for (int r = 0; r < 4; ++r) nav[rt][r] = sa[nrow0 + rt * 16 + lk * 4 + r]; \
                navmax = fmaxf(fmaxf(FMAX4(nav[0][0], nav[0][1], nav[0][2], nav[0][3]), \
                                     FMAX4(nav[1][0], nav[1][1], nav[1][2], nav[1][3])), \
                               fmaxf(FMAX4(nav[2][0], nav[2][1], nav[2][2], nav[2][3]), \
                                     FMAX4(nav[3][0], nav[3][1], nav[3][2], nav[3][3]))); \
                __builtin_amdgcn_sched_barrier(0);                                   \
            }                                                                        \
            bi = nbi; bj = nbj;                                                      \
        }                                                                            \
    }

    #pragma unroll
    for (int ii = 0; ii < 11; ++ii) {
        STEP_BODY(2 * ii,     accA, accB)
        STEP_BODY(2 * ii + 1, accB, accA)
    }

    // ---- final pending flush (last tile's epilogue) ----
    if (pend) {
        if (ext) {
            EPILOGUE_BODY(accB, bufNb[1][0], bufNb[1][1])
        } else {
            EPILOGUE_BODY(accA, bufNb[0][0], bufNb[0][1])
        }
    }
#undef STEP_BODY
#undef EPILOGUE_BODY

    // ---- single flush, spread over cache-line slots ----
    #pragma unroll
    for (int off = 32; off; off >>= 1) lsum += __shfl_xor(lsum, off, 64);
    if (lane == 0) wsum[wave] = lsum;
    __syncthreads();
    if (tid == 0) {
        float s = (wsum[0] + wsum[1]) + (wsum[2] + wsum[3]);
        int slot = combo * NSLOT + (bid & (NSLOT - 1));
        atomicAdd(&partial[slot * SLOT_STRIDE], s);
    }
}

__global__ void final_kernel(const float* __restrict__ partial, float* __restrict__ out) {
    __shared__ float s3[3];
    int tid = threadIdx.x;
    if (tid < 3) s3[tid] = 0.f;
    __syncthreads();
    if (tid < 3 * NSLOT) {
        float v = partial[tid * SLOT_STRIDE];
        atomicAdd(&s3[tid / NSLOT], v);
    }
    __syncthreads();
    if (tid == 0) {
        double inv = 1.0 / ((double)NN * (double)NN * 2.5066282746310002);  // N^2 * sqrt(2*pi)
        double mxx = (double)s3[0] * inv;
        double mzz = (double)s3[1] * inv;
        double mxz = (double)s3[2] * inv;
        double v = log(sqrt(mxx * mzz + 1e-5) / (mxz + 1e-5));
        out[0] = (float)v;
    }
}

extern "C" void kernel_launch(void* const* d_in, const int* in_sizes, int n_in,
                              void* d_out, int out_size, void* d_ws, size_t ws_size,
                              hipStream_t stream) {
    const float* X = (const float*)d_in[0];
    const float* Z = (const float*)d_in[1];
    char* ws = (char*)d_ws;
    __hip_bfloat16* XbF = (__hip_bfloat16*)(ws);
    __hip_bfloat16* ZbF = (__hip_bfloat16*)(ws + 1048576);
    float* na = (float*)(ws + 2097152);
    float* nb = (float*)(ws + 2097152 + 32768);
    float* partial = (float*)(ws + 2097152 + 65536);

    hipLaunchKernelGGL(prep_kernel, dim3(256), dim3(256), 0, stream,
                       X, Z, XbF, ZbF, na, nb, partial);
    hipLaunchKernelGGL(mmd_kernel, dim3(NBLOCKS), dim3(256), 0, stream, XbF, ZbF, na, nb, partial);
    hipLaunchKernelGGL(final_kernel, dim3(1), dim3(128), 0, stream, partial, (float*)d_out);
}

// Round 23
// 30.749 us; speedup vs baseline: 3.5344x; 3.5344x over previous
//
#include <hip/hip_runtime.h>
#include <hip/hip_bf16.h>
#include <math.h>

#define NN 8192
#define DD 64
// Block tile 256x32: 4 waves STACKED (each 64x32), all sharing one 4KB B
// tile -> cross-wave L1 reuse. Balanced single-round grid: 768 blocks
// (exactly 3/CU), blocks 0..511 do 22 tiles, 512..767 do 21.
// Region boundaries: 4224 = 22*192, 8448 = 22*384, and 21-tile blocks start
// at 11264 > 8448 -> every block is combo-pure (verified arithmetic).
#define BJ_MAX 256              // 32-col tiles
#define T1B 4224                // sym tiles per combo: sum_{si<32}(256-8si)
#define T2B (2*T1B)             // 8448
#define TILES_TOTAL 16640       // 2*4224 + 32*256
#define NBLOCKS 768
#define EXT_CUT 512             // blocks < EXT_CUT run 22 tiles, else 21
#define NSLOT 32
#define SLOT_STRIDE 16          // floats -> 64B per slot

// Fragment-order layout: panel p = 16 source rows; chunk lane L holds
// row (p*16 + (L&15)), bf16 elems [ks*32 + (L>>4)*8, +8).
#define PANEL_ELEMS 1024        // 16 rows * 64 elems

typedef __bf16 bf16x8 __attribute__((ext_vector_type(8)));
typedef float f32x4 __attribute__((ext_vector_type(4)));

#if defined(__has_builtin)
#if __has_builtin(__builtin_amdgcn_exp2f)
#define EXP2F __builtin_amdgcn_exp2f
#endif
#endif
#ifndef EXP2F
#define EXP2F exp2f
#endif

// max3-friendly reductions (clang folds nested fmaxf to v_max3_f32)
#define FMAX3(a,b,c) fmaxf(fmaxf((a),(b)),(c))
#define FMAX4(a,b,c,d) fmaxf(FMAX3((a),(b),(c)),(d))

// ws layout:
//   [0,        1048576)  XbF bf16 [512 panels][2 ks][64 lanes][8]  (fragment order)
//   [1048576,  2097152)  ZbF bf16 same
//   [2097152, +32768)    na  f32  [8192]   ( = -log2(e) * ||x_i||^2 )
//   [+32768,  +65536)    nb  f32  [8192]
//   [+65536,  +71680)    partial f32 [3*NSLOT*SLOT_STRIDE]

__global__ __launch_bounds__(256) void prep_kernel(
        const float* __restrict__ X, const float* __restrict__ Z,
        __hip_bfloat16* __restrict__ XbF, __hip_bfloat16* __restrict__ ZbF,
        float* __restrict__ na, float* __restrict__ nb,
        float* __restrict__ partial) {
    int tid = threadIdx.x;
    int gw = blockIdx.x * 4 + (tid >> 6);    // panel index in [0, 1024)
    int lane = tid & 63;
    int lm = lane & 15, lk = lane >> 4;
    const float* src = (gw < 512) ? X : Z;
    __hip_bfloat16* dst = (gw < 512) ? XbF : ZbF;
    float* nrm = (gw < 512) ? na : nb;
    int p = (gw < 512) ? gw : gw - 512;
    int row = p * 16 + lm;

    float s = 0.f;
    #pragma unroll
    for (int ks = 0; ks < 2; ++ks) {
        const float4* q = (const float4*)(src + (size_t)row * DD + ks * 32 + lk * 8);
        float4 u = q[0], v = q[1];
        float w[8] = {u.x, u.y, u.z, u.w, v.x, v.y, v.z, v.w};
        unsigned int h[8];
        #pragma unroll
        for (int r = 0; r < 8; ++r) {
            __hip_bfloat16 b = __float2bfloat16(w[r]);
            h[r] = *(unsigned short*)&b;
            float xr = __bfloat162float(b);
            s = fmaf(xr, xr, s);
        }
        uint4 pk;
        pk.x = h[0] | (h[1] << 16); pk.y = h[2] | (h[3] << 16);
        pk.z = h[4] | (h[5] << 16); pk.w = h[6] | (h[7] << 16);
        *(uint4*)(dst + (size_t)p * PANEL_ELEMS + ks * 512 + lane * 8) = pk;
    }
    s += __shfl_xor(s, 16, 64);
    s += __shfl_xor(s, 32, 64);
    if (lk == 0) nrm[row] = -1.4426950408889634f * s;

    if (blockIdx.x == 0) {
        for (int i = tid; i < 3 * NSLOT * SLOT_STRIDE; i += 256) partial[i] = 0.f;
    }
}

// Best-known kernel (R19, 30.9us): 256x32 shared-B tiles, register dbuf
// depth-1, fragment-order contiguous loads, two-level max3 gate, setprio,
// (256,3), balanced single-round grid. Falsified alternatives: LDS staging
// (R13 +4us), depth-2 prefetch (R15 +1us), no-dbuf 4/CU (R17 +4us), fused
// finalization (R20 +8us), acc double-pipeline (R22 spill +74us).
__global__ __launch_bounds__(256, 3) void mmd_kernel(
        const __hip_bfloat16* __restrict__ XbFh, const __hip_bfloat16* __restrict__ ZbFh,
        const float* __restrict__ na, const float* __restrict__ nb,
        float* __restrict__ partial) {
    int tid = threadIdx.x;
    int wave = tid >> 6, lane = tid & 63;
    int lm = lane & 15;   // frag row (within 16) / C col
    int lk = lane >> 4;   // k-group of 8 / C row group of 4
    __shared__ float wsum[4];
    const float C2 = 2.8853900817779268f;  // 2*log2(e)
    const int bid = blockIdx.x;
    const bool ext = (bid < EXT_CUT);      // 22 tiles if true, else 21

    // ---- map block's first tile (once) ----
    int t0 = bid * 21 + (ext ? bid : EXT_CUT);
    int combo, bi, bj;      // bi = 256-row stripe index
    if (t0 < T2B) {
        combo = (t0 < T1B) ? 0 : 1;
        int tt = t0 - (combo ? T1B : 0);
        // cum(si) = 260si - 4si^2
        int rr = (int)((65.0f - sqrtf(4225.0f - (float)tt)) * 0.5f);
        rr = rr < 0 ? 0 : (rr > 31 ? 31 : rr);
        while (rr > 0 && 260 * rr - 4 * rr * rr > tt) --rr;
        while (260 * (rr + 1) - 4 * (rr + 1) * (rr + 1) <= tt) ++rr;
        bi = rr;
        bj = 8 * rr + (tt - (260 * rr - 4 * rr * rr));
    } else {
        combo = 2;
        int rem = t0 - T2B;
        bi = rem >> 8;
        bj = rem & 255;
    }
    const bool sym = (combo != 2);
    const __bf16 *A, *B;
    const float *sa, *sb;
    const __bf16* XbF = (const __bf16*)XbFh;
    const __bf16* ZbF = (const __bf16*)ZbFh;
    if (combo == 0)      { A = XbF; B = XbF; sa = na; sb = na; }
    else if (combo == 1) { A = ZbF; B = ZbF; sa = nb; sb = nb; }
    else                 { A = XbF; B = ZbF; sa = na; sb = nb; }

    // ---- A fragments + row norms for current stripe ----
    bf16x8 af[2][4];
    float nav[4][4], navrtmax[4], navmax;
    {
        int pA = bi * 16 + wave * 4;
        #pragma unroll
        for (int ks = 0; ks < 2; ++ks)
            #pragma unroll
            for (int rt = 0; rt < 4; ++rt)
                af[ks][rt] = *(const bf16x8*)(A + (size_t)(pA + rt) * PANEL_ELEMS + ks * 512 + lane * 8);
        int row0 = bi * 256 + wave * 64;
        #pragma unroll
        for (int rt = 0; rt < 4; ++rt) {
            #pragma unroll
            for (int r = 0; r < 4; ++r) nav[rt][r] = sa[row0 + rt * 16 + lk * 4 + r];
            navrtmax[rt] = FMAX4(nav[rt][0], nav[rt][1], nav[rt][2], nav[rt][3]);
        }
        navmax = FMAX4(navrtmax[0], navrtmax[1], navrtmax[2], navrtmax[3]);
    }

    // ---- prefetch B for first tile (32 cols: panels bj*2, bj*2+1) ----
    bf16x8 bufB[2][2][2];   // [buf][ks][ct]
    float bufNb[2][2];
    {
        int pB = bj * 2;
        #pragma unroll
        for (int ks = 0; ks < 2; ++ks)
            #pragma unroll
            for (int ct = 0; ct < 2; ++ct)
                bufB[0][ks][ct] = *(const bf16x8*)(B + (size_t)(pB + ct) * PANEL_ELEMS + ks * 512 + lane * 8);
        int col0 = bj * 32;
        #pragma unroll
        for (int ct = 0; ct < 2; ++ct) bufNb[0][ct] = sb[col0 + ct * 16 + lm];
    }

    float lsum = 0.f;

    #pragma unroll
    for (int it = 0; it < 22; ++it) {
        if (it < 21 || ext) {
            const int cur = it & 1, nxt = cur ^ 1;
            const bool havenext = (it < 20) || (it == 20 && ext);
            int row0 = bi * 256 + wave * 64;
            int col0 = bj * 32;
            bool above = sym && (col0 >= row0 + 64);     // quadrant strictly above diag
            bool elemw = sym && !above;                  // per-element weights
            float tileScale = above ? 2.f : 1.f;

            // next tile coords + B prefetch (independent of current tile)
            int nbi = bi, nbj = bj;
            if (havenext) {
                nbj = bj + 1;
                if (nbj == BJ_MAX) { nbi = bi + 1; nbj = sym ? 8 * nbi : 0; }
                int npB = nbj * 2;
                #pragma unroll
                for (int ks = 0; ks < 2; ++ks)
                    #pragma unroll
                    for (int ct = 0; ct < 2; ++ct)
                        bufB[nxt][ks][ct] = *(const bf16x8*)(B + (size_t)(npB + ct) * PANEL_ELEMS + ks * 512 + lane * 8);
                int ncol0 = nbj * 32;
                #pragma unroll
                for (int ct = 0; ct < 2; ++ct) bufNb[nxt][ct] = sb[ncol0 + ct * 16 + lm];
            }
            // Fence: prefetch loads must ISSUE here, before the MFMA cluster.
            __builtin_amdgcn_sched_barrier(0);

            // ---- MFMA + gate, wave-priority boosted ----
            __builtin_amdgcn_s_setprio(1);
            f32x4 acc[4][2] = {};
            #pragma unroll
            for (int ks = 0; ks < 2; ++ks)
                #pragma unroll
                for (int rt = 0; rt < 4; ++rt)
                    #pragma unroll
                    for (int ct = 0; ct < 2; ++ct)
                        acc[rt][ct] = __builtin_amdgcn_mfma_f32_16x16x32_bf16(
                            af[ks][rt], bufB[cur][ks][ct], acc[rt][ct], 0, 0, 0);

            // ---- tile-level gate (max3-shaped): one branch for closed tiles ----
            float m00 = FMAX4(acc[0][0][0], acc[0][0][1], acc[0][0][2], acc[0][0][3]);
            float m01 = FMAX4(acc[0][1][0], acc[0][1][1], acc[0][1][2], acc[0][1][3]);
            float m10 = FMAX4(acc[1][0][0], acc[1][0][1], acc[1][0][2], acc[1][0][3]);
            float m11 = FMAX4(acc[1][1][0], acc[1][1][1], acc[1][1][2], acc[1][1][3]);
            float m20 = FMAX4(acc[2][0][0], acc[2][0][1], acc[2][0][2], acc[2][0][3]);
            float m21 = FMAX4(acc[2][1][0], acc[2][1][1], acc[2][1][2], acc[2][1][3]);
            float m30 = FMAX4(acc[3][0][0], acc[3][0][1], acc[3][0][2], acc[3][0][3]);
            float m31 = FMAX4(acc[3][1][0], acc[3][1][1], acc[3][1][2], acc[3][1][3]);
            float gmax = fmaxf(FMAX4(m00, m01, m10, m11), FMAX4(m20, m21, m30, m31));
            __builtin_amdgcn_s_setprio(0);
            float nbmax = fmaxf(bufNb[cur][0], bufNb[cur][1]);
            float tileBound = fmaf(gmax, C2, navmax + nbmax);
            if (__any(tileBound > -30.f)) {
                // ---- per-frag gated epilogue (rare: diag-adjacent tiles) ----
                #pragma unroll
                for (int rt = 0; rt < 4; ++rt) {
                    #pragma unroll
                    for (int ct = 0; ct < 2; ++ct) {
                        float fm = FMAX4(acc[rt][ct][0], acc[rt][ct][1], acc[rt][ct][2], acc[rt][ct][3]);
                        float fb = fmaf(fm, C2, navrtmax[rt] + bufNb[cur][ct]);
                        if (__any(fb > -30.f)) {
                            float base = bufNb[cur][ct];
                            float a0 = fmaf(acc[rt][ct][0], C2, nav[rt][0] + base);
                            float a1 = fmaf(acc[rt][ct][1], C2, nav[rt][1] + base);
                            float a2 = fmaf(acc[rt][ct][2], C2, nav[rt][2] + base);
                            float a3 = fmaf(acc[rt][ct][3], C2, nav[rt][3] + base);
                            float e0 = EXP2F(fminf(a0, 0.f));
                            float e1 = EXP2F(fminf(a1, 0.f));
                            float e2 = EXP2F(fminf(a2, 0.f));
                            float e3 = EXP2F(fminf(a3, 0.f));
                            if (elemw) {
                                int gcol = col0 + ct * 16 + lm;
                                int gr = row0 + rt * 16 + lk * 4;
                                e0 *= (gr + 0 < gcol) ? 2.f : ((gr + 0 == gcol) ? 1.f : 0.f);
                                e1 *= (gr + 1 < gcol) ? 2.f : ((gr + 1 == gcol) ? 1.f : 0.f);
                                e2 *= (gr + 2 < gcol) ? 2.f : ((gr + 2 == gcol) ? 1.f : 0.f);
                                e3 *= (gr + 3 < gcol) ? 2.f : ((gr + 3 == gcol) ? 1.f : 0.f);
                                lsum += (e0 + e1) + (e2 + e3);
                            } else {
                                lsum += tileScale * ((e0 + e1) + (e2 + e3));
                            }
                        }
                    }
                }
            }

            // ---- stripe change: reload A (after epilogue consumed nav) ----
            if (havenext && nbi != bi) {
                int npA = nbi * 16 + wave * 4;
                #pragma unroll
                for (int ks = 0; ks < 2; ++ks)
                    #pragma unroll
                    for (int rt = 0; rt < 4; ++rt)
                        af[ks][rt] = *(const bf16x8*)(A + (size_t)(npA + rt) * PANEL_ELEMS + ks * 512 + lane * 8);
                int nrow0 = nbi * 256 + wave * 64;
                #pragma unroll
                for (int rt = 0; rt < 4; ++rt) {
                    #pragma unroll
                    for (int r = 0; r < 4; ++r) nav[rt][r] = sa[nrow0 + rt * 16 + lk * 4 + r];
                    navrtmax[rt] = FMAX4(nav[rt][0], nav[rt][1], nav[rt][2], nav[rt][3]);
                }
                navmax = FMAX4(navrtmax[0], navrtmax[1], navrtmax[2], navrtmax[3]);
                __builtin_amdgcn_sched_barrier(0);
            }
            bi = nbi; bj = nbj;
        }
    }

    // ---- single flush, spread over cache-line slots ----
    #pragma unroll
    for (int off = 32; off; off >>= 1) lsum += __shfl_xor(lsum, off, 64);
    if (lane == 0) wsum[wave] = lsum;
    __syncthreads();
    if (tid == 0) {
        float s = (wsum[0] + wsum[1]) + (wsum[2] + wsum[3]);
        int slot = combo * NSLOT + (bid & (NSLOT - 1));
        atomicAdd(&partial[slot * SLOT_STRIDE], s);
    }
}

__global__ void final_kernel(const float* __restrict__ partial, float* __restrict__ out) {
    __shared__ float s3[3];
    int tid = threadIdx.x;
    if (tid < 3) s3[tid] = 0.f;
    __syncthreads();
    if (tid < 3 * NSLOT) {
        float v = partial[tid * SLOT_STRIDE];
        atomicAdd(&s3[tid / NSLOT], v);
    }
    __syncthreads();
    if (tid == 0) {
        double inv = 1.0 / ((double)NN * (double)NN * 2.5066282746310002);  // N^2 * sqrt(2*pi)
        double mxx = (double)s3[0] * inv;
        double mzz = (double)s3[1] * inv;
        double mxz = (double)s3[2] * inv;
        double v = log(sqrt(mxx * mzz + 1e-5) / (mxz + 1e-5));
        out[0] = (float)v;
    }
}

extern "C" void kernel_launch(void* const* d_in, const int* in_sizes, int n_in,
                              void* d_out, int out_size, void* d_ws, size_t ws_size,
                              hipStream_t stream) {
    const float* X = (const float*)d_in[0];
    const float* Z = (const float*)d_in[1];
    char* ws = (char*)d_ws;
    __hip_bfloat16* XbF = (__hip_bfloat16*)(ws);
    __hip_bfloat16* ZbF = (__hip_bfloat16*)(ws + 1048576);
    float* na = (float*)(ws + 2097152);
    float* nb = (float*)(ws + 2097152 + 32768);
    float* partial = (float*)(ws + 2097152 + 65536);

    hipLaunchKernelGGL(prep_kernel, dim3(256), dim3(256), 0, stream,
                       X, Z, XbF, ZbF, na, nb, partial);
    hipLaunchKernelGGL(mmd_kernel, dim3(NBLOCKS), dim3(256), 0, stream, XbF, ZbF, na, nb, partial);
    hipLaunchKernelGGL(final_kernel, dim3(1), dim3(128), 0, stream, partial, (float*)d_out);
}